// Round 14
// baseline (123.832 us; speedup 1.0000x reference)
//
#include <hip/hip_runtime.h>
#include <hip/hip_bf16.h>
#include <hip/hip_fp16.h>

typedef __attribute__((ext_vector_type(8))) short bf16x8;
typedef __attribute__((ext_vector_type(4))) short bf16x4;
typedef __attribute__((ext_vector_type(4))) _Float16 f16x4;
typedef __attribute__((ext_vector_type(4))) float f32x4;
typedef __attribute__((ext_vector_type(4))) unsigned u32x4;
typedef __attribute__((ext_vector_type(4))) int i32x4;

constexpr int Bn = 4, Hn = 16, S = 2048, D = 64;
constexpr int BQ = 128;   // q rows per block
constexpr float LOG2E = 1.44269504088896340736f;
constexpr float CD2f = (2.0f / ((float)S * (float)S)) * LOG2E;

__device__ __forceinline__ unsigned cvtpk(float lo, float hi) {
    unsigned r;
    asm("v_cvt_pk_bf16_f32 %0, %1, %2" : "=v"(r) : "v"(lo), "v"(hi));
    return r;
}

__device__ __forceinline__ unsigned pkrtz(float lo, float hi) {
    auto h = __builtin_amdgcn_cvt_pkrtz(lo, hi);   // __fp16 ext_vector(2)
    return __builtin_bit_cast(unsigned, h);
}

__device__ __forceinline__ unsigned pkmul(unsigned a, unsigned b) {
    unsigned r;
    asm("v_pk_mul_f16 %0, %1, %2" : "=v"(r) : "v"(a), "v"(b));
    return r;
}

__device__ __forceinline__ f32x4 mfma16h(f16x4 a, f16x4 b, f32x4 c) {
#if __has_builtin(__builtin_amdgcn_mfma_f32_16x16x16f16)
    return __builtin_amdgcn_mfma_f32_16x16x16f16(a, b, c, 0, 0, 0);
#else
    asm volatile("v_mfma_f32_16x16x16_f16 %0, %1, %2, %0"
                 : "+v"(c) : "v"(a), "v"(b));
    return c;
#endif
}

__device__ __forceinline__ f32x4 mfma16(bf16x4 a, bf16x4 b, f32x4 c) {
#if __has_builtin(__builtin_amdgcn_mfma_f32_16x16x16bf16_1k)
    return __builtin_amdgcn_mfma_f32_16x16x16bf16_1k(a, b, c, 0, 0, 0);
#else
    asm volatile("v_mfma_f32_16x16x16_bf16 %0, %1, %2, %0"
                 : "+v"(c) : "v"(a), "v"(b));
    return c;
#endif
}

// async global->LDS, 16B per lane; lds base must be wave-uniform; g is per-lane
__device__ __forceinline__ void gload16(const short* g, short* lds) {
    __builtin_amdgcn_global_load_lds(
        (const __attribute__((address_space(1))) unsigned*)g,
        (__attribute__((address_space(3))) unsigned*)lds,
        16, 0, 0);
}

// ---------------- kernel 1: mask compaction (per batch) ----------------
__global__ void compact_mask(const void* __restrict__ maskg,
                             int* __restrict__ idxp, int* __restrict__ Mg) {
    const int b = blockIdx.x, t = threadIdx.x;
    __shared__ int wsum[4];
    __shared__ int Msh;

    const unsigned* mu = (const unsigned*)maskg;
    bool is_bytes = false;
    #pragma unroll 8
    for (int i = 0; i < 64; ++i) is_bytes |= (mu[i] > 1u);

    int keep[8]; int cnt = 0;
    #pragma unroll
    for (int i = 0; i < 8; ++i) {
        const int key = t * 8 + i;
        int m;
        if (is_bytes) m = ((const unsigned char*)maskg)[b * S + key];
        else          m = ((const int*)maskg)[b * S + key];
        keep[i] = (m == 0);
        cnt += keep[i];
    }
    const int l = t & 63, w = t >> 6;
    int pre = cnt;
    #pragma unroll
    for (int d = 1; d < 64; d <<= 1) {
        int v = __shfl_up(pre, d, 64);
        if (l >= d) pre += v;
    }
    if (l == 63) wsum[w] = pre;
    __syncthreads();
    int base = 0;
    for (int i = 0; i < w; ++i) base += wsum[i];
    int offs = base + pre - cnt;
    #pragma unroll
    for (int i = 0; i < 8; ++i)
        if (keep[i]) idxp[b * S + (offs++)] = t * 8 + i;
    if (t == 255) Msh = base + pre;
    __syncthreads();
    const int M = Msh;
    for (int i = M + t; i < S; i += 256) idxp[b * S + i] = 0;   // pad
    if (M == 0)   // degenerate: uniform softmax; identity index, flag via sign
        for (int i = t; i < S; i += 256) idxp[b * S + i] = i;
    if (t == 0) Mg[b] = (M == 0) ? -1 : M;
}

// ------------- kernel 2: pack compacted K (bf16) / V (fp16) to workspace -------------
// K' layout: [bh][key][d]            (tile = 64 consecutive keys => contiguous 8KB)
// V' layout: [bh][tile][dv][key64]   (contiguous 8KB per tile, transposed, fp16)
__global__ void pack_kv(const float* __restrict__ Kg, const float* __restrict__ Vg,
                        const int* __restrict__ idxp, const int* __restrict__ Mg,
                        short* __restrict__ Kw, short* __restrict__ Vw) {
    const int bh = blockIdx.x, b = bh >> 4;
    const int ck0 = blockIdx.y * 256;
    const int t = threadIdx.x;
    const int Mraw = Mg[b];
    const int M = (Mraw < 0) ? S : Mraw;
    if (ck0 >= M) return;
    const int* idxb = idxp + b * S;
    const float* Kp = Kg + (size_t)bh * S * D;
    const float* Vp = Vg + (size_t)bh * S * D;

    {
        const int dc = (t & 7) * 8;
        #pragma unroll
        for (int tile = 0; tile < 4; ++tile)
            #pragma unroll
            for (int it = 0; it < 2; ++it) {
                const int key = ck0 + tile * 64 + (t >> 3) + it * 32;
                u32x4 pk = u32x4{0u, 0u, 0u, 0u};
                if (key < M) {
                    const float* src = Kp + (size_t)idxb[key] * D + dc;
                    #pragma unroll
                    for (int jj = 0; jj < 4; ++jj)
                        pk[jj] = cvtpk(src[2 * jj], src[2 * jj + 1]);
                }
                *(u32x4*)(Kw + ((size_t)bh * S + key) * D + dc) = pk;
            }
    }
    {
        const int dv = t & 63;
        const int kb = (t >> 6) * 16;
        #pragma unroll
        for (int tile = 0; tile < 4; ++tile) {
            const int tg = (ck0 >> 6) + tile;
            float f[16];
            #pragma unroll
            for (int i = 0; i < 16; ++i) {
                const int key = ck0 + tile * 64 + kb + i;
                float v = 0.f;
                if (key < M) {
                    int row = idxb[key];
                    row = __builtin_amdgcn_readfirstlane(row);
                    v = Vp[(size_t)row * D + dv];
                }
                f[i] = v;
            }
            u32x4 p0, p1;
            #pragma unroll
            for (int jj = 0; jj < 4; ++jj) {
                p0[jj] = pkrtz(f[2 * jj], f[2 * jj + 1]);       // fp16 V
                p1[jj] = pkrtz(f[8 + 2 * jj], f[9 + 2 * jj]);
            }
            short* dst = Vw + (((size_t)bh * 32 + tg) * 64 + dv) * 64 + kb;
            *(u32x4*)dst = p0;
            *(u32x4*)(dst + 8) = p1;
        }
    }
}

// ------- kernel 3: 4-wave, gload_lds, fp16 pair-decay, fp16 PV -------
__global__ __launch_bounds__(256, 4) void attn_packed(
    const float* __restrict__ Qg, const short* __restrict__ Kw,
    const short* __restrict__ Vw, const int* __restrict__ idxp,
    const int* __restrict__ Mg, float* __restrict__ outg)
{
    __shared__ alignas(16) short Kt[2][64][64];   // swizzled granules (bf16)
    __shared__ alignas(16) short Vt[2][64][64];   // swizzled granules (fp16)
    __shared__ alignas(16) unsigned dpair[2176];  // (fp16 d(i), fp16 d(i+16))
    __shared__ alignas(16) int   idxs[2][64];     // staged original key indices
    // LDS total = 41984 B -> 3 blocks/CU

    const int bid  = blockIdx.x;
    const int lblk = ((bid & 7) << 7) | (bid >> 3);   // XCD swizzle (bijective)
    const int qt   = lblk & 15;
    const int bh   = lblk >> 4;
    const int b    = bh >> 4;
    const int q0   = qt * BQ;

    const float* Qp   = Qg + ((size_t)bh * S + q0) * D;
    const short* Ksrc = Kw + (size_t)bh * S * D;
    const short* Vsrc = Vw + (size_t)bh * 32 * 64 * 64;
    float*       Op   = outg + ((size_t)bh * S + q0) * D;
    const int*   idxb = idxp + b * S;

    const int t  = threadIdx.x;       // 0..255, 4 waves
    const int w  = t >> 6;
    const int l  = t & 63;
    const int lr = l & 15;
    const int lg = l >> 4;
    const int lx = lr & 7;

    const int  Mraw    = Mg[b];
    const bool uniform = (Mraw < 0);
    const int  M       = uniform ? S : Mraw;
    const int  ntiles  = (M + 63) >> 6;

    // staging geometry: 2 passes x (256 threads x 16B) cover one 8KB tile
    int so[2], ld[2];
    #pragma unroll
    for (int p = 0; p < 2; ++p) {
        const int r = (p * 4 + w) * 8 + (l >> 3);          // linear row
        so[p] = r * 64 + (((l & 7) ^ (r & 7)) << 3);       // pre-swizzled src (shorts)
        ld[p] = (p * 4 + w) * 512;                         // wave-uniform LDS chunk
    }

    // ---- stage tile 0 (async) + idxs ----
    gload16(Ksrc + so[0], &Kt[0][0][0] + ld[0]);
    gload16(Ksrc + so[1], &Kt[0][0][0] + ld[1]);
    gload16(Vsrc + so[0], &Vt[0][0][0] + ld[0]);
    gload16(Vsrc + so[1], &Vt[0][0][0] + ld[1]);
    if (t < 64) idxs[0][t] = idxb[t];

    // ---- decay pair table: dpair[i] = (d(q0+i-2047), d(q0+i-2031)) fp16x2 ----
    for (int i = t; i < 2176; i += 256) {
        const float r0 = (float)(q0 + i - 2047);
        const float r1 = r0 + 16.0f;
        const float d0 = __builtin_exp2f(-CD2f * r0 * r0);
        const float d1 = __builtin_exp2f(-CD2f * r1 * r1);
        dpair[i] = pkrtz(d0, d1);
    }

    // ---- Q fragments (B-operand), scaled; zeroed in uniform mode ----
    const float qscale = uniform ? 0.0f : 0.125f * LOG2E;
    bf16x8 qf[2][2];
    #pragma unroll
    for (int rt = 0; rt < 2; ++rt) {
        const int row = w * 32 + rt * 16 + lr;
        #pragma unroll
        for (int g = 0; g < 2; ++g) {
            const float* src = Qp + row * D + g * 32 + lg * 8;
            union { unsigned u[4]; bf16x8 v; } cv;
            #pragma unroll
            for (int jj = 0; jj < 4; ++jj)
                cv.u[jj] = cvtpk(src[2 * jj] * qscale, src[2 * jj + 1] * qscale);
            qf[rt][g] = cv.v;
        }
    }

    f32x4 Oacc[2][4];
    #pragma unroll
    for (int rt = 0; rt < 2; ++rt)
        #pragma unroll
        for (int dt = 0; dt < 4; ++dt) Oacc[rt][dt] = f32x4{0.f, 0.f, 0.f, 0.f};
    float lrun[2] = {0.f, 0.f};

    const int qi0 = w * 32 + lr + 2047;   // rt0 table index base (rt1 = pair hi)

    asm volatile("s_waitcnt vmcnt(0)" ::: "memory");
    __syncthreads();

    int c = 0;
    for (int tt = 0; tt < ntiles; ++tt) {
        const int  rem  = M - tt * 64;
        const bool last = (rem <= 64);

        // ---- stage next tile (async; lands during compute) + idxs ----
        if (tt + 1 < ntiles) {
            const short* kp = Ksrc + (size_t)(tt + 1) * 4096;
            const short* vp = Vsrc + (size_t)(tt + 1) * 4096;
            gload16(kp + so[0], &Kt[c ^ 1][0][0] + ld[0]);
            gload16(kp + so[1], &Kt[c ^ 1][0][0] + ld[1]);
            gload16(vp + so[0], &Vt[c ^ 1][0][0] + ld[0]);
            gload16(vp + so[1], &Vt[c ^ 1][0][0] + ld[1]);
            if (t < 64) idxs[c ^ 1][t] = idxb[(tt + 1) * 64 + t];
        }

        const char* kbase = (const char*)&Kt[c][0][0];
        const char* vbase = (const char*)&Vt[c][0][0];

        #pragma unroll
        for (int kt = 0; kt < 4; ++kt) {
            // K fragments (swizzled b128) -> QK^T for both rt; C-init = -2 (shift)
            const bf16x8 kf0 = *(const bf16x8*)(kbase + (kt * 16 + lr) * 128
                                                + ((lg ^ lx) << 4));
            const bf16x8 kf1 = *(const bf16x8*)(kbase + (kt * 16 + lr) * 128
                                                + (((4 + lg) ^ lx) << 4));
            f32x4 s0 = f32x4{-2.f, -2.f, -2.f, -2.f};
            f32x4 s1 = f32x4{-2.f, -2.f, -2.f, -2.f};
            __builtin_amdgcn_s_setprio(1);
            s0 = __builtin_amdgcn_mfma_f32_16x16x32_bf16(kf0, qf[0][0], s0, 0, 0, 0);
            s0 = __builtin_amdgcn_mfma_f32_16x16x32_bf16(kf1, qf[0][1], s0, 0, 0, 0);
            s1 = __builtin_amdgcn_mfma_f32_16x16x32_bf16(kf0, qf[1][0], s1, 0, 0, 0);
            s1 = __builtin_amdgcn_mfma_f32_16x16x32_bf16(kf1, qf[1][1], s1, 0, 0, 0);
            __builtin_amdgcn_s_setprio(0);

            // original key indices from LDS (broadcast b128, conflict-free)
            const i32x4 iv = *(const i32x4*)&idxs[c][kt * 16 + lg * 4];

            // decay pairs: one b32 read covers both rt (rt1 = rt0 + 16)
            const unsigned dq0 = dpair[qi0 - iv[0]];
            const unsigned dq1 = dpair[qi0 - iv[1]];
            const unsigned dq2 = dpair[qi0 - iv[2]];
            const unsigned dq3 = dpair[qi0 - iv[3]];

            // fixed-shift softmax: p = 2^(s-2); shift cancels in O/l
            float pa0 = __builtin_exp2f(s0[0]), pb0 = __builtin_exp2f(s1[0]);
            float pa1 = __builtin_exp2f(s0[1]), pb1 = __builtin_exp2f(s1[1]);
            float pa2 = __builtin_exp2f(s0[2]), pb2 = __builtin_exp2f(s1[2]);
            float pa3 = __builtin_exp2f(s0[3]), pb3 = __builtin_exp2f(s1[3]);
            if (last) {   // zero padded keys (wave-uniform branch)
                const int ck = kt * 16 + lg * 4;
                pa0 = (ck + 0 < rem) ? pa0 : 0.f;  pb0 = (ck + 0 < rem) ? pb0 : 0.f;
                pa1 = (ck + 1 < rem) ? pa1 : 0.f;  pb1 = (ck + 1 < rem) ? pb1 : 0.f;
                pa2 = (ck + 2 < rem) ? pa2 : 0.f;  pb2 = (ck + 2 < rem) ? pb2 : 0.f;
                pa3 = (ck + 3 < rem) ? pa3 : 0.f;  pb3 = (ck + 3 < rem) ? pb3 : 0.f;
            }
            lrun[0] += (pa0 + pa1) + (pa2 + pa3);
            lrun[1] += (pb0 + pb1) + (pb2 + pb3);

            // pack p across rt, apply both decays with one pk_mul per element
            const unsigned pd0 = pkmul(pkrtz(pa0, pb0), dq0);
            const unsigned pd1 = pkmul(pkrtz(pa1, pb1), dq1);
            const unsigned pd2 = pkmul(pkrtz(pa2, pb2), dq2);
            const unsigned pd3 = pkmul(pkrtz(pa3, pb3), dq3);

            // reassemble per-rt B-fragments (f16): lo halves -> rt0, hi -> rt1
            union { unsigned u[2]; f16x4 v; } xb0, xb1;
            xb0.u[0] = __builtin_amdgcn_perm(pd1, pd0, 0x05040100u);
            xb0.u[1] = __builtin_amdgcn_perm(pd3, pd2, 0x05040100u);
            xb1.u[0] = __builtin_amdgcn_perm(pd1, pd0, 0x07060302u);
            xb1.u[1] = __builtin_amdgcn_perm(pd3, pd2, 0x07060302u);

            // PV for this 16-key slab (fp16 MFMA); vA shared across rt
            __builtin_amdgcn_s_setprio(1);
            #pragma unroll
            for (int dt = 0; dt < 4; ++dt) {
                const f16x4 vA = *(const f16x4*)(vbase + (dt * 16 + lr) * 128
                          + ((((2 * kt + (lg >> 1)) ^ lx) << 4) | ((lg & 1) << 3)));
                Oacc[0][dt] = mfma16h(vA, xb0.v, Oacc[0][dt]);
                Oacc[1][dt] = mfma16h(vA, xb1.v, Oacc[1][dt]);
            }
            __builtin_amdgcn_s_setprio(0);
        }

        asm volatile("s_waitcnt vmcnt(0)" ::: "memory");
        __syncthreads();
        c ^= 1;
    }

    // ---- epilogue ----
    #pragma unroll
    for (int rt = 0; rt < 2; ++rt) {
        float ls = lrun[rt];
        ls += __shfl_xor(ls, 16, 64);
        ls += __shfl_xor(ls, 32, 64);
        const float inv = 1.0f / ls;
        const int row = w * 32 + rt * 16 + lr;
        #pragma unroll
        for (int dt = 0; dt < 4; ++dt) {
            f32x4 o = Oacc[rt][dt];
            o[0] *= inv; o[1] *= inv; o[2] *= inv; o[3] *= inv;
            *(f32x4*)&Op[(size_t)row * D + dt * 16 + lg * 4] = o;
        }
    }
}

// ------- kernel 4: gather fallback (used if ws too small) -------
__global__ __launch_bounds__(256, 3) void attn_gather(
    const float* __restrict__ Qg, const float* __restrict__ Kg,
    const float* __restrict__ Vg, const int* __restrict__ idxp,
    const int* __restrict__ Mg, float* __restrict__ outg)
{
    __shared__ alignas(16) short Kt[64][72];
    __shared__ alignas(16) short Vt[64][72];
    __shared__ alignas(16) float dtab[2176];
    __shared__ alignas(16) int   idxs[64];

    const int blk = blockIdx.x;
    const int qt  = blk & 15;
    const int bh  = blk >> 4;
    const int b   = bh >> 4;
    const int q0  = qt * BQ;

    const float* Qp = Qg + ((size_t)bh * S + q0) * D;
    const float* Kp = Kg + (size_t)bh * S * D;
    const float* Vp = Vg + (size_t)bh * S * D;
    float*       Op = outg + ((size_t)bh * S + q0) * D;
    const int*   idxb = idxp + b * S;

    const int t  = threadIdx.x;
    const int w  = t >> 6;
    const int l  = t & 63;
    const int lr = l & 15;
    const int lg = l >> 4;

    const int  Mraw    = Mg[b];
    const bool uniform = (Mraw < 0);
    const int  M       = uniform ? S : Mraw;

    for (int i = t; i < 2176; i += 256) {
        const float r = (float)(q0 + i - 2047);
        dtab[i] = __builtin_exp2f(-CD2f * r * r);
    }

    const float qscale = uniform ? 0.0f : 0.125f * LOG2E;
    bf16x8 qf[2][2];
    #pragma unroll
    for (int rt = 0; rt < 2; ++rt) {
        const int row = w * 32 + rt * 16 + lr;
        #pragma unroll
        for (int g = 0; g < 2; ++g) {
            const float* src = Qp + row * D + g * 32 + lg * 8;
            union { unsigned u[4]; bf16x8 v; } cv;
            #pragma unroll
            for (int jj = 0; jj < 4; ++jj)
                cv.u[jj] = cvtpk(src[2 * jj] * qscale, src[2 * jj + 1] * qscale);
            qf[rt][g] = cv.v;
        }
    }

    f32x4 Oacc[2][4];
    #pragma unroll
    for (int rt = 0; rt < 2; ++rt)
        #pragma unroll
        for (int dt = 0; dt < 4; ++dt) Oacc[rt][dt] = f32x4{0.f, 0.f, 0.f, 0.f};
    float lrun[2] = {0.f, 0.f};

    const int qrl2047 = w * 32 + lr + 2047;

    for (int kv = 0; kv < M; kv += 64) {
        const int  rem  = M - kv;
        const bool last = (rem <= 64);
        __syncthreads();
        {
            const int key = t >> 3;
            const int dc  = (t & 7) * 8;
            #pragma unroll
            for (int it = 0; it < 2; ++it) {
                const int row = idxb[kv + key + it * 32];
                const float* src = Kp + (size_t)row * D + dc;
                u32x4 pk;
                #pragma unroll
                for (int jj = 0; jj < 4; ++jj)
                    pk[jj] = cvtpk(src[2 * jj], src[2 * jj + 1]);
                *(u32x4*)&Kt[key + it * 32][dc] = pk;
            }
        }
        if (t < 64) idxs[t] = idxb[kv + t];
        {
            const int dv = t & 63;
            const int kb = (t >> 6) * 16;
            float f[16];
            #pragma unroll
            for (int i = 0; i < 16; ++i) {
                int row = idxb[kv + kb + i];
                row = __builtin_amdgcn_readfirstlane(row);
                f[i] = Vp[(size_t)row * D + dv];
            }
            u32x4 p0, p1;
            #pragma unroll
            for (int jj = 0; jj < 4; ++jj) {
                p0[jj] = cvtpk(f[2 * jj], f[2 * jj + 1]);
                p1[jj] = cvtpk(f[8 + 2 * jj], f[9 + 2 * jj]);
            }
            *(u32x4*)&Vt[dv][kb]     = p0;
            *(u32x4*)&Vt[dv][kb + 8] = p1;
        }
        __syncthreads();

        bf16x8 kf[4][2];
        #pragma unroll
        for (int kt = 0; kt < 4; ++kt)
            #pragma unroll
            for (int g = 0; g < 2; ++g)
                kf[kt][g] = *(const bf16x8*)&Kt[kt * 16 + lr][g * 32 + lg * 8];

        bf16x4 Xb[2][4];
        #pragma unroll
        for (int rt = 0; rt < 2; ++rt) {
            f32x4 sc[4];
            #pragma unroll
            for (int kt = 0; kt < 4; ++kt) {
                f32x4 acc = f32x4{-16.f, -16.f, -16.f, -16.f};
                acc = __builtin_amdgcn_mfma_f32_16x16x32_bf16(kf[kt][0], qf[rt][0], acc, 0, 0, 0);
                acc = __builtin_amdgcn_mfma_f32_16x16x32_bf16(kf[kt][1], qf[rt][1], acc, 0, 0, 0);
                sc[kt] = acc;
            }
            const int qi = qrl2047 + rt * 16;
            float lp = 0.f;
            #pragma unroll
            for (int kt = 0; kt < 4; ++kt) {
                const i32x4 iv = *(const i32x4*)&idxs[kt * 16 + lg * 4];
                float p0 = __builtin_exp2f(sc[kt][0]);
                float p1 = __builtin_exp2f(sc[kt][1]);
                float p2 = __builtin_exp2f(sc[kt][2]);
                float p3 = __builtin_exp2f(sc[kt][3]);
                if (last) {
                    const int ck = kt * 16 + lg * 4;
                    p0 = (ck + 0 < rem) ? p0 : 0.f;
                    p1 = (ck + 1 < rem) ? p1 : 0.f;
                    p2 = (ck + 2 < rem) ? p2 : 0.f;
                    p3 = (ck + 3 < rem) ? p3 : 0.f;
                }
                lp += (p0 + p1) + (p2 + p3);
                const float d0 = dtab[qi - iv[0]];
                const float d1 = dtab[qi - iv[1]];
                const float d2 = dtab[qi - iv[2]];
                const float d3 = dtab[qi - iv[3]];
                union { unsigned u[2]; bf16x4 v; } cx;
                cx.u[0] = cvtpk(p0 * d0, p1 * d1);
                cx.u[1] = cvtpk(p2 * d2, p3 * d3);
                Xb[rt][kt] = cx.v;
            }
            lrun[rt] += lp;
        }

        #pragma unroll
        for (int kt = 0; kt < 4; ++kt) {
            bf16x4 vA[4];
            #pragma unroll
            for (int dt = 0; dt < 4; ++dt)
                vA[dt] = *(const bf16x4*)&Vt[dt * 16 + lr][kt * 16 + lg * 4];
            #pragma unroll
            for (int dt = 0; dt < 4; ++dt) {
                Oacc[0][dt] = mfma16(vA[dt], Xb[0][kt], Oacc[0][dt]);
                Oacc[1][dt] = mfma16(vA[dt], Xb[1][kt], Oacc[1][dt]);
            }
        }
    }

    #pragma unroll
    for (int rt = 0; rt < 2; ++rt) {
        float ls = lrun[rt];
        ls += __shfl_xor(ls, 16, 64);
        ls += __shfl_xor(ls, 32, 64);
        const float inv = 1.0f / ls;
        const int row = w * 32 + rt * 16 + lr;
        #pragma unroll
        for (int dt = 0; dt < 4; ++dt) {
            f32x4 o = Oacc[rt][dt];
            o[0] *= inv; o[1] *= inv; o[2] *= inv; o[3] *= inv;
            *(f32x4*)&Op[(size_t)row * D + dt * 16 + lg * 4] = o;
        }
    }
}

extern "C" void kernel_launch(void* const* d_in, const int* in_sizes, int n_in,
                              void* d_out, int out_size, void* d_ws, size_t ws_size,
                              hipStream_t stream) {
    const float* Q = (const float*)d_in[0];
    const float* K = (const float*)d_in[1];
    const float* V = (const float*)d_in[2];
    const void*  M = d_in[3];
    float* out = (float*)d_out;

    int* idxp = (int*)d_ws;                       // Bn*S ints
    int* Mg   = idxp + Bn * S;                    // Bn ints
    size_t base = (((size_t)(Bn * S + Bn) * 4) + 255) & ~(size_t)255;
    short* Kw = (short*)((char*)d_ws + base);     // Bn*Hn*S*D bf16
    short* Vw = Kw + (size_t)Bn * Hn * S * D;     // Bn*Hn*S*D fp16
    const size_t need = base + 2 * (size_t)Bn * Hn * S * D * sizeof(short);

    compact_mask<<<dim3(Bn), dim3(256), 0, stream>>>(M, idxp, Mg);
    const int nblk = Bn * Hn * (S / BQ);   // 1024
    if (ws_size >= need) {
        pack_kv<<<dim3(Bn * Hn, S / 256), dim3(256), 0, stream>>>(K, V, idxp, Mg, Kw, Vw);
        attn_packed<<<dim3(nblk), dim3(256), 0, stream>>>(Q, Kw, Vw, idxp, Mg, out);
    } else {
        attn_gather<<<dim3(nblk), dim3(256), 0, stream>>>(Q, K, V, idxp, Mg, out);
    }
}

// Round 15
// 114.709 us; speedup vs baseline: 1.0795x; 1.0795x over previous
//
#include <hip/hip_runtime.h>
#include <hip/hip_bf16.h>
#include <hip/hip_fp16.h>

typedef __attribute__((ext_vector_type(8))) short bf16x8;
typedef __attribute__((ext_vector_type(4))) short bf16x4;
typedef __attribute__((ext_vector_type(4))) _Float16 f16x4;
typedef __attribute__((ext_vector_type(4))) float f32x4;
typedef __attribute__((ext_vector_type(4))) unsigned u32x4;
typedef __attribute__((ext_vector_type(4))) int i32x4;

constexpr int Bn = 4, Hn = 16, S = 2048, D = 64;
constexpr int BQ = 128;   // q rows per block
constexpr float LOG2E = 1.44269504088896340736f;
constexpr float CD2f = (2.0f / ((float)S * (float)S)) * LOG2E;

__device__ __forceinline__ unsigned cvtpk(float lo, float hi) {
    unsigned r;
    asm("v_cvt_pk_bf16_f32 %0, %1, %2" : "=v"(r) : "v"(lo), "v"(hi));
    return r;
}

__device__ __forceinline__ unsigned pkrtz(float lo, float hi) {
    auto h = __builtin_amdgcn_cvt_pkrtz(lo, hi);   // __fp16 ext_vector(2)
    return __builtin_bit_cast(unsigned, h);
}

__device__ __forceinline__ unsigned pkmul(unsigned a, unsigned b) {
    unsigned r;
    asm("v_pk_mul_f16 %0, %1, %2" : "=v"(r) : "v"(a), "v"(b));
    return r;
}

__device__ __forceinline__ f32x4 mfma16h(f16x4 a, f16x4 b, f32x4 c) {
#if __has_builtin(__builtin_amdgcn_mfma_f32_16x16x16f16)
    return __builtin_amdgcn_mfma_f32_16x16x16f16(a, b, c, 0, 0, 0);
#else
    asm volatile("v_mfma_f32_16x16x16_f16 %0, %1, %2, %0"
                 : "+v"(c) : "v"(a), "v"(b));
    return c;
#endif
}

__device__ __forceinline__ f32x4 mfma16(bf16x4 a, bf16x4 b, f32x4 c) {
#if __has_builtin(__builtin_amdgcn_mfma_f32_16x16x16bf16_1k)
    return __builtin_amdgcn_mfma_f32_16x16x16bf16_1k(a, b, c, 0, 0, 0);
#else
    asm volatile("v_mfma_f32_16x16x16_bf16 %0, %1, %2, %0"
                 : "+v"(c) : "v"(a), "v"(b));
    return c;
#endif
}

// async global->LDS, 16B per lane; lds base must be wave-uniform; g is per-lane
__device__ __forceinline__ void gload16(const short* g, short* lds) {
    __builtin_amdgcn_global_load_lds(
        (const __attribute__((address_space(1))) unsigned*)g,
        (__attribute__((address_space(3))) unsigned*)lds,
        16, 0, 0);
}

// ---------------- kernel 1: mask compaction (per batch) ----------------
__global__ void compact_mask(const void* __restrict__ maskg,
                             int* __restrict__ idxp, int* __restrict__ Mg) {
    const int b = blockIdx.x, t = threadIdx.x;
    __shared__ int wsum[4];
    __shared__ int Msh;

    const unsigned* mu = (const unsigned*)maskg;
    bool is_bytes = false;
    #pragma unroll 8
    for (int i = 0; i < 64; ++i) is_bytes |= (mu[i] > 1u);

    int keep[8]; int cnt = 0;
    #pragma unroll
    for (int i = 0; i < 8; ++i) {
        const int key = t * 8 + i;
        int m;
        if (is_bytes) m = ((const unsigned char*)maskg)[b * S + key];
        else          m = ((const int*)maskg)[b * S + key];
        keep[i] = (m == 0);
        cnt += keep[i];
    }
    const int l = t & 63, w = t >> 6;
    int pre = cnt;
    #pragma unroll
    for (int d = 1; d < 64; d <<= 1) {
        int v = __shfl_up(pre, d, 64);
        if (l >= d) pre += v;
    }
    if (l == 63) wsum[w] = pre;
    __syncthreads();
    int base = 0;
    for (int i = 0; i < w; ++i) base += wsum[i];
    int offs = base + pre - cnt;
    #pragma unroll
    for (int i = 0; i < 8; ++i)
        if (keep[i]) idxp[b * S + (offs++)] = t * 8 + i;
    if (t == 255) Msh = base + pre;
    __syncthreads();
    const int M = Msh;
    for (int i = M + t; i < S; i += 256) idxp[b * S + i] = 0;   // pad
    if (M == 0)   // degenerate: uniform softmax; identity index, flag via sign
        for (int i = t; i < S; i += 256) idxp[b * S + i] = i;
    if (t == 0) Mg[b] = (M == 0) ? -1 : M;
}

// ------------- kernel 2: pack compacted K (bf16) / V (fp16) to workspace -------------
// K' layout: [bh][key][d]            (tile = 64 consecutive keys => contiguous 8KB)
// V' layout: [bh][tile][dv][key64]   (contiguous 8KB per tile, transposed, fp16)
__global__ void pack_kv(const float* __restrict__ Kg, const float* __restrict__ Vg,
                        const int* __restrict__ idxp, const int* __restrict__ Mg,
                        short* __restrict__ Kw, short* __restrict__ Vw) {
    const int bh = blockIdx.x, b = bh >> 4;
    const int ck0 = blockIdx.y * 256;
    const int t = threadIdx.x;
    const int Mraw = Mg[b];
    const int M = (Mraw < 0) ? S : Mraw;
    if (ck0 >= M) return;
    const int* idxb = idxp + b * S;
    const float* Kp = Kg + (size_t)bh * S * D;
    const float* Vp = Vg + (size_t)bh * S * D;

    {
        const int dc = (t & 7) * 8;
        #pragma unroll
        for (int tile = 0; tile < 4; ++tile)
            #pragma unroll
            for (int it = 0; it < 2; ++it) {
                const int key = ck0 + tile * 64 + (t >> 3) + it * 32;
                u32x4 pk = u32x4{0u, 0u, 0u, 0u};
                if (key < M) {
                    const float* src = Kp + (size_t)idxb[key] * D + dc;
                    #pragma unroll
                    for (int jj = 0; jj < 4; ++jj)
                        pk[jj] = cvtpk(src[2 * jj], src[2 * jj + 1]);
                }
                *(u32x4*)(Kw + ((size_t)bh * S + key) * D + dc) = pk;
            }
    }
    {
        const int dv = t & 63;
        const int kb = (t >> 6) * 16;
        #pragma unroll
        for (int tile = 0; tile < 4; ++tile) {
            const int tg = (ck0 >> 6) + tile;
            float f[16];
            #pragma unroll
            for (int i = 0; i < 16; ++i) {
                const int key = ck0 + tile * 64 + kb + i;
                float v = 0.f;
                if (key < M) {
                    int row = idxb[key];
                    row = __builtin_amdgcn_readfirstlane(row);
                    v = Vp[(size_t)row * D + dv];
                }
                f[i] = v;
            }
            u32x4 p0, p1;
            #pragma unroll
            for (int jj = 0; jj < 4; ++jj) {
                p0[jj] = pkrtz(f[2 * jj], f[2 * jj + 1]);       // fp16 V
                p1[jj] = pkrtz(f[8 + 2 * jj], f[9 + 2 * jj]);
            }
            short* dst = Vw + (((size_t)bh * 32 + tg) * 64 + dv) * 64 + kb;
            *(u32x4*)dst = p0;
            *(u32x4*)(dst + 8) = p1;
        }
    }
}

// ------- kernel 3: 4-wave, gload_lds, fp16 single-table pair-decay, fp16 PV -------
__global__ __launch_bounds__(256, 4) void attn_packed(
    const float* __restrict__ Qg, const short* __restrict__ Kw,
    const short* __restrict__ Vw, const int* __restrict__ idxp,
    const int* __restrict__ Mg, float* __restrict__ outg)
{
    __shared__ alignas(16) short Kt[2][64][64];         // swizzled granules (bf16)
    __shared__ alignas(16) short Vt[2][64][64];         // swizzled granules (fp16)
    __shared__ alignas(16) unsigned short dtab[2176];   // fp16 decay table
    __shared__ alignas(16) int idxs[2][64];             // staged original key indices
    // LDS total = 37632 B -> 4 blocks/CU

    const int bid  = blockIdx.x;
    const int lblk = ((bid & 7) << 7) | (bid >> 3);   // XCD swizzle (bijective)
    const int qt   = lblk & 15;
    const int bh   = lblk >> 4;
    const int b    = bh >> 4;
    const int q0   = qt * BQ;

    const float* Qp   = Qg + ((size_t)bh * S + q0) * D;
    const short* Ksrc = Kw + (size_t)bh * S * D;
    const short* Vsrc = Vw + (size_t)bh * 32 * 64 * 64;
    float*       Op   = outg + ((size_t)bh * S + q0) * D;
    const int*   idxb = idxp + b * S;

    const int t  = threadIdx.x;       // 0..255, 4 waves
    const int w  = t >> 6;
    const int l  = t & 63;
    const int lr = l & 15;
    const int lg = l >> 4;
    const int lx = lr & 7;

    const int  Mraw    = Mg[b];
    const bool uniform = (Mraw < 0);
    const int  M       = uniform ? S : Mraw;
    const int  ntiles  = (M + 63) >> 6;

    // staging geometry: 2 passes x (256 threads x 16B) cover one 8KB tile
    int so[2], ld[2];
    #pragma unroll
    for (int p = 0; p < 2; ++p) {
        const int r = (p * 4 + w) * 8 + (l >> 3);          // linear row
        so[p] = r * 64 + (((l & 7) ^ (r & 7)) << 3);       // pre-swizzled src (shorts)
        ld[p] = (p * 4 + w) * 512;                         // wave-uniform LDS chunk
    }

    // ---- stage tile 0 (async) + idxs ----
    gload16(Ksrc + so[0], &Kt[0][0][0] + ld[0]);
    gload16(Ksrc + so[1], &Kt[0][0][0] + ld[1]);
    gload16(Vsrc + so[0], &Vt[0][0][0] + ld[0]);
    gload16(Vsrc + so[1], &Vt[0][0][0] + ld[1]);
    if (t < 64) idxs[0][t] = idxb[t];

    // ---- decay table (fp16): dtab[i] = 2^(-CD2*(q0+i-2047)^2) ----
    for (int i = t; i < 2176; i += 256) {
        const float r = (float)(q0 + i - 2047);
        dtab[i] = (unsigned short)pkrtz(__builtin_exp2f(-CD2f * r * r), 0.f);
    }

    // ---- Q fragments (B-operand), scaled; zeroed in uniform mode ----
    const float qscale = uniform ? 0.0f : 0.125f * LOG2E;
    bf16x8 qf[2][2];
    #pragma unroll
    for (int rt = 0; rt < 2; ++rt) {
        const int row = w * 32 + rt * 16 + lr;
        #pragma unroll
        for (int g = 0; g < 2; ++g) {
            const float* src = Qp + row * D + g * 32 + lg * 8;
            union { unsigned u[4]; bf16x8 v; } cv;
            #pragma unroll
            for (int jj = 0; jj < 4; ++jj)
                cv.u[jj] = cvtpk(src[2 * jj] * qscale, src[2 * jj + 1] * qscale);
            qf[rt][g] = cv.v;
        }
    }

    f32x4 Oacc[2][4];
    #pragma unroll
    for (int rt = 0; rt < 2; ++rt)
        #pragma unroll
        for (int dt = 0; dt < 4; ++dt) Oacc[rt][dt] = f32x4{0.f, 0.f, 0.f, 0.f};
    float lrun[2] = {0.f, 0.f};

    const int qiA = w * 32 + lr + 2047;   // rt0 table index base
    const int qiB = qiA + 16;             // rt1

    asm volatile("s_waitcnt vmcnt(0)" ::: "memory");
    __syncthreads();

    int c = 0;
    for (int tt = 0; tt < ntiles; ++tt) {
        const int  rem  = M - tt * 64;
        const bool last = (rem <= 64);

        // ---- stage next tile (async; lands during compute) + idxs ----
        if (tt + 1 < ntiles) {
            const short* kp = Ksrc + (size_t)(tt + 1) * 4096;
            const short* vp = Vsrc + (size_t)(tt + 1) * 4096;
            gload16(kp + so[0], &Kt[c ^ 1][0][0] + ld[0]);
            gload16(kp + so[1], &Kt[c ^ 1][0][0] + ld[1]);
            gload16(vp + so[0], &Vt[c ^ 1][0][0] + ld[0]);
            gload16(vp + so[1], &Vt[c ^ 1][0][0] + ld[1]);
            if (t < 64) idxs[c ^ 1][t] = idxb[(tt + 1) * 64 + t];
        }

        const char* kbase = (const char*)&Kt[c][0][0];
        const char* vbase = (const char*)&Vt[c][0][0];

        #pragma unroll
        for (int kt = 0; kt < 4; ++kt) {
            // K fragments (swizzled b128) -> QK^T for both rt; C-init = -2 (shift)
            const bf16x8 kf0 = *(const bf16x8*)(kbase + (kt * 16 + lr) * 128
                                                + ((lg ^ lx) << 4));
            const bf16x8 kf1 = *(const bf16x8*)(kbase + (kt * 16 + lr) * 128
                                                + (((4 + lg) ^ lx) << 4));
            f32x4 s0 = f32x4{-2.f, -2.f, -2.f, -2.f};
            f32x4 s1 = f32x4{-2.f, -2.f, -2.f, -2.f};
            __builtin_amdgcn_s_setprio(1);
            s0 = __builtin_amdgcn_mfma_f32_16x16x32_bf16(kf0, qf[0][0], s0, 0, 0, 0);
            s0 = __builtin_amdgcn_mfma_f32_16x16x32_bf16(kf1, qf[0][1], s0, 0, 0, 0);
            s1 = __builtin_amdgcn_mfma_f32_16x16x32_bf16(kf0, qf[1][0], s1, 0, 0, 0);
            s1 = __builtin_amdgcn_mfma_f32_16x16x32_bf16(kf1, qf[1][1], s1, 0, 0, 0);
            __builtin_amdgcn_s_setprio(0);

            // original key indices from LDS (broadcast b128, conflict-free)
            const i32x4 iv = *(const i32x4*)&idxs[c][kt * 16 + lg * 4];

            // decay pair words from single fp16 table: lo = rt0, hi = rt1
            const unsigned dq0 = (unsigned)dtab[qiA - iv[0]] | ((unsigned)dtab[qiB - iv[0]] << 16);
            const unsigned dq1 = (unsigned)dtab[qiA - iv[1]] | ((unsigned)dtab[qiB - iv[1]] << 16);
            const unsigned dq2 = (unsigned)dtab[qiA - iv[2]] | ((unsigned)dtab[qiB - iv[2]] << 16);
            const unsigned dq3 = (unsigned)dtab[qiA - iv[3]] | ((unsigned)dtab[qiB - iv[3]] << 16);

            // fixed-shift softmax: p = 2^(s-2); shift cancels in O/l
            float pa0 = __builtin_exp2f(s0[0]), pb0 = __builtin_exp2f(s1[0]);
            float pa1 = __builtin_exp2f(s0[1]), pb1 = __builtin_exp2f(s1[1]);
            float pa2 = __builtin_exp2f(s0[2]), pb2 = __builtin_exp2f(s1[2]);
            float pa3 = __builtin_exp2f(s0[3]), pb3 = __builtin_exp2f(s1[3]);
            if (last) {   // zero padded keys (wave-uniform branch)
                const int ck = kt * 16 + lg * 4;
                pa0 = (ck + 0 < rem) ? pa0 : 0.f;  pb0 = (ck + 0 < rem) ? pb0 : 0.f;
                pa1 = (ck + 1 < rem) ? pa1 : 0.f;  pb1 = (ck + 1 < rem) ? pb1 : 0.f;
                pa2 = (ck + 2 < rem) ? pa2 : 0.f;  pb2 = (ck + 2 < rem) ? pb2 : 0.f;
                pa3 = (ck + 3 < rem) ? pa3 : 0.f;  pb3 = (ck + 3 < rem) ? pb3 : 0.f;
            }
            lrun[0] += (pa0 + pa1) + (pa2 + pa3);
            lrun[1] += (pb0 + pb1) + (pb2 + pb3);

            // pack p across rt, apply both decays with one pk_mul per element
            const unsigned pd0 = pkmul(pkrtz(pa0, pb0), dq0);
            const unsigned pd1 = pkmul(pkrtz(pa1, pb1), dq1);
            const unsigned pd2 = pkmul(pkrtz(pa2, pb2), dq2);
            const unsigned pd3 = pkmul(pkrtz(pa3, pb3), dq3);

            // reassemble per-rt B-fragments (f16): lo halves -> rt0, hi -> rt1
            union { unsigned u[2]; f16x4 v; } xb0, xb1;
            xb0.u[0] = __builtin_amdgcn_perm(pd1, pd0, 0x05040100u);
            xb0.u[1] = __builtin_amdgcn_perm(pd3, pd2, 0x05040100u);
            xb1.u[0] = __builtin_amdgcn_perm(pd1, pd0, 0x07060302u);
            xb1.u[1] = __builtin_amdgcn_perm(pd3, pd2, 0x07060302u);

            // PV for this 16-key slab (fp16 MFMA); vA shared across rt
            __builtin_amdgcn_s_setprio(1);
            #pragma unroll
            for (int dt = 0; dt < 4; ++dt) {
                const f16x4 vA = *(const f16x4*)(vbase + (dt * 16 + lr) * 128
                          + ((((2 * kt + (lg >> 1)) ^ lx) << 4) | ((lg & 1) << 3)));
                Oacc[0][dt] = mfma16h(vA, xb0.v, Oacc[0][dt]);
                Oacc[1][dt] = mfma16h(vA, xb1.v, Oacc[1][dt]);
            }
            __builtin_amdgcn_s_setprio(0);
        }

        asm volatile("s_waitcnt vmcnt(0)" ::: "memory");
        __syncthreads();
        c ^= 1;
    }

    // ---- epilogue ----
    #pragma unroll
    for (int rt = 0; rt < 2; ++rt) {
        float ls = lrun[rt];
        ls += __shfl_xor(ls, 16, 64);
        ls += __shfl_xor(ls, 32, 64);
        const float inv = 1.0f / ls;
        const int row = w * 32 + rt * 16 + lr;
        #pragma unroll
        for (int dt = 0; dt < 4; ++dt) {
            f32x4 o = Oacc[rt][dt];
            o[0] *= inv; o[1] *= inv; o[2] *= inv; o[3] *= inv;
            *(f32x4*)&Op[(size_t)row * D + dt * 16 + lg * 4] = o;
        }
    }
}

// ------- kernel 4: gather fallback (used if ws too small) -------
__global__ __launch_bounds__(256, 3) void attn_gather(
    const float* __restrict__ Qg, const float* __restrict__ Kg,
    const float* __restrict__ Vg, const int* __restrict__ idxp,
    const int* __restrict__ Mg, float* __restrict__ outg)
{
    __shared__ alignas(16) short Kt[64][72];
    __shared__ alignas(16) short Vt[64][72];
    __shared__ alignas(16) float dtab[2176];
    __shared__ alignas(16) int   idxs[64];

    const int blk = blockIdx.x;
    const int qt  = blk & 15;
    const int bh  = blk >> 4;
    const int b   = bh >> 4;
    const int q0  = qt * BQ;

    const float* Qp = Qg + ((size_t)bh * S + q0) * D;
    const float* Kp = Kg + (size_t)bh * S * D;
    const float* Vp = Vg + (size_t)bh * S * D;
    float*       Op = outg + ((size_t)bh * S + q0) * D;
    const int*   idxb = idxp + b * S;

    const int t  = threadIdx.x;
    const int w  = t >> 6;
    const int l  = t & 63;
    const int lr = l & 15;
    const int lg = l >> 4;

    const int  Mraw    = Mg[b];
    const bool uniform = (Mraw < 0);
    const int  M       = uniform ? S : Mraw;

    for (int i = t; i < 2176; i += 256) {
        const float r = (float)(q0 + i - 2047);
        dtab[i] = __builtin_exp2f(-CD2f * r * r);
    }

    const float qscale = uniform ? 0.0f : 0.125f * LOG2E;
    bf16x8 qf[2][2];
    #pragma unroll
    for (int rt = 0; rt < 2; ++rt) {
        const int row = w * 32 + rt * 16 + lr;
        #pragma unroll
        for (int g = 0; g < 2; ++g) {
            const float* src = Qp + row * D + g * 32 + lg * 8;
            union { unsigned u[4]; bf16x8 v; } cv;
            #pragma unroll
            for (int jj = 0; jj < 4; ++jj)
                cv.u[jj] = cvtpk(src[2 * jj] * qscale, src[2 * jj + 1] * qscale);
            qf[rt][g] = cv.v;
        }
    }

    f32x4 Oacc[2][4];
    #pragma unroll
    for (int rt = 0; rt < 2; ++rt)
        #pragma unroll
        for (int dt = 0; dt < 4; ++dt) Oacc[rt][dt] = f32x4{0.f, 0.f, 0.f, 0.f};
    float lrun[2] = {0.f, 0.f};

    const int qrl2047 = w * 32 + lr + 2047;

    for (int kv = 0; kv < M; kv += 64) {
        const int  rem  = M - kv;
        const bool last = (rem <= 64);
        __syncthreads();
        {
            const int key = t >> 3;
            const int dc  = (t & 7) * 8;
            #pragma unroll
            for (int it = 0; it < 2; ++it) {
                const int row = idxb[kv + key + it * 32];
                const float* src = Kp + (size_t)row * D + dc;
                u32x4 pk;
                #pragma unroll
                for (int jj = 0; jj < 4; ++jj)
                    pk[jj] = cvtpk(src[2 * jj], src[2 * jj + 1]);
                *(u32x4*)&Kt[key + it * 32][dc] = pk;
            }
        }
        if (t < 64) idxs[t] = idxb[kv + t];
        {
            const int dv = t & 63;
            const int kb = (t >> 6) * 16;
            float f[16];
            #pragma unroll
            for (int i = 0; i < 16; ++i) {
                int row = idxb[kv + kb + i];
                row = __builtin_amdgcn_readfirstlane(row);
                f[i] = Vp[(size_t)row * D + dv];
            }
            u32x4 p0, p1;
            #pragma unroll
            for (int jj = 0; jj < 4; ++jj) {
                p0[jj] = cvtpk(f[2 * jj], f[2 * jj + 1]);
                p1[jj] = cvtpk(f[8 + 2 * jj], f[9 + 2 * jj]);
            }
            *(u32x4*)&Vt[dv][kb]     = p0;
            *(u32x4*)&Vt[dv][kb + 8] = p1;
        }
        __syncthreads();

        bf16x8 kf[4][2];
        #pragma unroll
        for (int kt = 0; kt < 4; ++kt)
            #pragma unroll
            for (int g = 0; g < 2; ++g)
                kf[kt][g] = *(const bf16x8*)&Kt[kt * 16 + lr][g * 32 + lg * 8];

        bf16x4 Xb[2][4];
        #pragma unroll
        for (int rt = 0; rt < 2; ++rt) {
            f32x4 sc[4];
            #pragma unroll
            for (int kt = 0; kt < 4; ++kt) {
                f32x4 acc = f32x4{-16.f, -16.f, -16.f, -16.f};
                acc = __builtin_amdgcn_mfma_f32_16x16x32_bf16(kf[kt][0], qf[rt][0], acc, 0, 0, 0);
                acc = __builtin_amdgcn_mfma_f32_16x16x32_bf16(kf[kt][1], qf[rt][1], acc, 0, 0, 0);
                sc[kt] = acc;
            }
            const int qi = qrl2047 + rt * 16;
            float lp = 0.f;
            #pragma unroll
            for (int kt = 0; kt < 4; ++kt) {
                const i32x4 iv = *(const i32x4*)&idxs[kt * 16 + lg * 4];
                float p0 = __builtin_exp2f(sc[kt][0]);
                float p1 = __builtin_exp2f(sc[kt][1]);
                float p2 = __builtin_exp2f(sc[kt][2]);
                float p3 = __builtin_exp2f(sc[kt][3]);
                if (last) {
                    const int ck = kt * 16 + lg * 4;
                    p0 = (ck + 0 < rem) ? p0 : 0.f;
                    p1 = (ck + 1 < rem) ? p1 : 0.f;
                    p2 = (ck + 2 < rem) ? p2 : 0.f;
                    p3 = (ck + 3 < rem) ? p3 : 0.f;
                }
                lp += (p0 + p1) + (p2 + p3);
                const float d0 = dtab[qi - iv[0]];
                const float d1 = dtab[qi - iv[1]];
                const float d2 = dtab[qi - iv[2]];
                const float d3 = dtab[qi - iv[3]];
                union { unsigned u[2]; bf16x4 v; } cx;
                cx.u[0] = cvtpk(p0 * d0, p1 * d1);
                cx.u[1] = cvtpk(p2 * d2, p3 * d3);
                Xb[rt][kt] = cx.v;
            }
            lrun[rt] += lp;
        }

        #pragma unroll
        for (int kt = 0; kt < 4; ++kt) {
            bf16x4 vA[4];
            #pragma unroll
            for (int dt = 0; dt < 4; ++dt)
                vA[dt] = *(const bf16x4*)&Vt[dt * 16 + lr][kt * 16 + lg * 4];
            #pragma unroll
            for (int dt = 0; dt < 4; ++dt) {
                Oacc[0][dt] = mfma16(vA[dt], Xb[0][kt], Oacc[0][dt]);
                Oacc[1][dt] = mfma16(vA[dt], Xb[1][kt], Oacc[1][dt]);
            }
        }
    }

    #pragma unroll
    for (int rt = 0; rt < 2; ++rt) {
        float ls = lrun[rt];
        ls += __shfl_xor(ls, 16, 64);
        ls += __shfl_xor(ls, 32, 64);
        const float inv = 1.0f / ls;
        const int row = w * 32 + rt * 16 + lr;
        #pragma unroll
        for (int dt = 0; dt < 4; ++dt) {
            f32x4 o = Oacc[rt][dt];
            o[0] *= inv; o[1] *= inv; o[2] *= inv; o[3] *= inv;
            *(f32x4*)&Op[(size_t)row * D + dt * 16 + lg * 4] = o;
        }
    }
}

extern "C" void kernel_launch(void* const* d_in, const int* in_sizes, int n_in,
                              void* d_out, int out_size, void* d_ws, size_t ws_size,
                              hipStream_t stream) {
    const float* Q = (const float*)d_in[0];
    const float* K = (const float*)d_in[1];
    const float* V = (const float*)d_in[2];
    const void*  M = d_in[3];
    float* out = (float*)d_out;

    int* idxp = (int*)d_ws;                       // Bn*S ints
    int* Mg   = idxp + Bn * S;                    // Bn ints
    size_t base = (((size_t)(Bn * S + Bn) * 4) + 255) & ~(size_t)255;
    short* Kw = (short*)((char*)d_ws + base);     // Bn*Hn*S*D bf16
    short* Vw = Kw + (size_t)Bn * Hn * S * D;     // Bn*Hn*S*D fp16
    const size_t need = base + 2 * (size_t)Bn * Hn * S * D * sizeof(short);

    compact_mask<<<dim3(Bn), dim3(256), 0, stream>>>(M, idxp, Mg);
    const int nblk = Bn * Hn * (S / BQ);   // 1024
    if (ws_size >= need) {
        pack_kv<<<dim3(Bn * Hn, S / 256), dim3(256), 0, stream>>>(K, V, idxp, Mg, Kw, Vw);
        attn_packed<<<dim3(nblk), dim3(256), 0, stream>>>(Q, Kw, Vw, idxp, Mg, out);
    } else {
        attn_gather<<<dim3(nblk), dim3(256), 0, stream>>>(Q, K, V, idxp, Mg, out);
    }
}

// Round 16
// 113.018 us; speedup vs baseline: 1.0957x; 1.0150x over previous
//
#include <hip/hip_runtime.h>
#include <hip/hip_bf16.h>
#include <hip/hip_fp16.h>

typedef __attribute__((ext_vector_type(8))) short bf16x8;
typedef __attribute__((ext_vector_type(4))) short bf16x4;
typedef __attribute__((ext_vector_type(4))) _Float16 f16x4;
typedef __attribute__((ext_vector_type(4))) float f32x4;
typedef __attribute__((ext_vector_type(4))) unsigned u32x4;
typedef __attribute__((ext_vector_type(4))) int i32x4;

constexpr int Bn = 4, Hn = 16, S = 2048, D = 64;
constexpr float LOG2E = 1.44269504088896340736f;
constexpr float CD2f = (2.0f / ((float)S * (float)S)) * LOG2E;

__device__ __forceinline__ unsigned cvtpk(float lo, float hi) {
    unsigned r;
    asm("v_cvt_pk_bf16_f32 %0, %1, %2" : "=v"(r) : "v"(lo), "v"(hi));
    return r;
}

__device__ __forceinline__ unsigned pkrtz(float lo, float hi) {
    auto h = __builtin_amdgcn_cvt_pkrtz(lo, hi);   // __fp16 ext_vector(2)
    return __builtin_bit_cast(unsigned, h);
}

__device__ __forceinline__ unsigned pkmul(unsigned a, unsigned b) {
    unsigned r;
    asm("v_pk_mul_f16 %0, %1, %2" : "=v"(r) : "v"(a), "v"(b));
    return r;
}

__device__ __forceinline__ f32x4 mfma16h(f16x4 a, f16x4 b, f32x4 c) {
#if __has_builtin(__builtin_amdgcn_mfma_f32_16x16x16f16)
    return __builtin_amdgcn_mfma_f32_16x16x16f16(a, b, c, 0, 0, 0);
#else
    asm volatile("v_mfma_f32_16x16x16_f16 %0, %1, %2, %0"
                 : "+v"(c) : "v"(a), "v"(b));
    return c;
#endif
}

__device__ __forceinline__ f32x4 mfma16(bf16x4 a, bf16x4 b, f32x4 c) {
#if __has_builtin(__builtin_amdgcn_mfma_f32_16x16x16bf16_1k)
    return __builtin_amdgcn_mfma_f32_16x16x16bf16_1k(a, b, c, 0, 0, 0);
#else
    asm volatile("v_mfma_f32_16x16x16_bf16 %0, %1, %2, %0"
                 : "+v"(c) : "v"(a), "v"(b));
    return c;
#endif
}

// async global->LDS, 16B per lane; lds base must be wave-uniform; g is per-lane
__device__ __forceinline__ void gload16(const short* g, short* lds) {
    __builtin_amdgcn_global_load_lds(
        (const __attribute__((address_space(1))) unsigned*)g,
        (__attribute__((address_space(3))) unsigned*)lds,
        16, 0, 0);
}

// ---------------- kernel 1: mask compaction (per batch) ----------------
__global__ void compact_mask(const void* __restrict__ maskg,
                             int* __restrict__ idxp, int* __restrict__ Mg) {
    const int b = blockIdx.x, t = threadIdx.x;
    __shared__ int wsum[4];
    __shared__ int Msh;

    const unsigned* mu = (const unsigned*)maskg;
    bool is_bytes = false;
    #pragma unroll 8
    for (int i = 0; i < 64; ++i) is_bytes |= (mu[i] > 1u);

    int keep[8]; int cnt = 0;
    #pragma unroll
    for (int i = 0; i < 8; ++i) {
        const int key = t * 8 + i;
        int m;
        if (is_bytes) m = ((const unsigned char*)maskg)[b * S + key];
        else          m = ((const int*)maskg)[b * S + key];
        keep[i] = (m == 0);
        cnt += keep[i];
    }
    const int l = t & 63, w = t >> 6;
    int pre = cnt;
    #pragma unroll
    for (int d = 1; d < 64; d <<= 1) {
        int v = __shfl_up(pre, d, 64);
        if (l >= d) pre += v;
    }
    if (l == 63) wsum[w] = pre;
    __syncthreads();
    int base = 0;
    for (int i = 0; i < w; ++i) base += wsum[i];
    int offs = base + pre - cnt;
    #pragma unroll
    for (int i = 0; i < 8; ++i)
        if (keep[i]) idxp[b * S + (offs++)] = t * 8 + i;
    if (t == 255) Msh = base + pre;
    __syncthreads();
    const int M = Msh;
    for (int i = M + t; i < S; i += 256) idxp[b * S + i] = 0;   // pad
    if (M == 0)   // degenerate: uniform softmax; identity index, flag via sign
        for (int i = t; i < S; i += 256) idxp[b * S + i] = i;
    if (t == 0) Mg[b] = (M == 0) ? -1 : M;
}

// ------------- kernel 2: pack compacted K (bf16) / V (fp16) to workspace -------------
// K' layout: [bh][key][d]            (tile = 64 consecutive keys => contiguous 8KB)
// V' layout: [bh][tile][dv][key64]   (contiguous 8KB per tile, transposed, fp16)
__global__ void pack_kv(const float* __restrict__ Kg, const float* __restrict__ Vg,
                        const int* __restrict__ idxp, const int* __restrict__ Mg,
                        short* __restrict__ Kw, short* __restrict__ Vw) {
    const int bh = blockIdx.x, b = bh >> 4;
    const int ck0 = blockIdx.y * 256;
    const int t = threadIdx.x;
    const int Mraw = Mg[b];
    const int M = (Mraw < 0) ? S : Mraw;
    if (ck0 >= M) return;
    const int* idxb = idxp + b * S;
    const float* Kp = Kg + (size_t)bh * S * D;
    const float* Vp = Vg + (size_t)bh * S * D;

    {
        const int dc = (t & 7) * 8;
        #pragma unroll
        for (int tile = 0; tile < 4; ++tile)
            #pragma unroll
            for (int it = 0; it < 2; ++it) {
                const int key = ck0 + tile * 64 + (t >> 3) + it * 32;
                u32x4 pk = u32x4{0u, 0u, 0u, 0u};
                if (key < M) {
                    const float* src = Kp + (size_t)idxb[key] * D + dc;
                    #pragma unroll
                    for (int jj = 0; jj < 4; ++jj)
                        pk[jj] = cvtpk(src[2 * jj], src[2 * jj + 1]);
                }
                *(u32x4*)(Kw + ((size_t)bh * S + key) * D + dc) = pk;
            }
    }
    {
        const int dv = t & 63;
        const int kb = (t >> 6) * 16;
        #pragma unroll
        for (int tile = 0; tile < 4; ++tile) {
            const int tg = (ck0 >> 6) + tile;
            float f[16];
            #pragma unroll
            for (int i = 0; i < 16; ++i) {
                const int key = ck0 + tile * 64 + kb + i;
                float v = 0.f;
                if (key < M) {
                    int row = idxb[key];
                    row = __builtin_amdgcn_readfirstlane(row);
                    v = Vp[(size_t)row * D + dv];
                }
                f[i] = v;
            }
            u32x4 p0, p1;
            #pragma unroll
            for (int jj = 0; jj < 4; ++jj) {
                p0[jj] = pkrtz(f[2 * jj], f[2 * jj + 1]);       // fp16 V
                p1[jj] = pkrtz(f[8 + 2 * jj], f[9 + 2 * jj]);
            }
            short* dst = Vw + (((size_t)bh * 32 + tg) * 64 + dv) * 64 + kb;
            *(u32x4*)dst = p0;
            *(u32x4*)(dst + 8) = p1;
        }
    }
}

// ------- kernel 3: 8-wave BQ=256, gload_lds, fp16 table pair-decay, fp16 PV -------
__global__ __launch_bounds__(512, 4) void attn_packed(
    const float* __restrict__ Qg, const short* __restrict__ Kw,
    const short* __restrict__ Vw, const int* __restrict__ idxp,
    const int* __restrict__ Mg, float* __restrict__ outg)
{
    __shared__ alignas(16) short Kt[2][64][64];         // swizzled granules (bf16)
    __shared__ alignas(16) short Vt[2][64][64];         // swizzled granules (fp16)
    __shared__ alignas(16) unsigned short dtab[2304];   // fp16 decay table (BQ=256 span)
    __shared__ alignas(16) int idxs[2][64];             // staged original key indices
    // LDS total = 16384*2 + 4608 + 512 = 37888 B

    const int bid  = blockIdx.x;
    const int lblk = ((bid & 7) << 6) | (bid >> 3);   // XCD swizzle (512 % 8 == 0)
    const int qt   = lblk & 7;                        // S/256 = 8 q-tiles
    const int bh   = lblk >> 3;
    const int b    = bh >> 4;
    const int q0   = qt * 256;

    const float* Qp   = Qg + ((size_t)bh * S + q0) * D;
    const short* Ksrc = Kw + (size_t)bh * S * D;
    const short* Vsrc = Vw + (size_t)bh * 32 * 64 * 64;
    float*       Op   = outg + ((size_t)bh * S + q0) * D;
    const int*   idxb = idxp + b * S;

    const int t  = threadIdx.x;       // 0..511, 8 waves x 32 q-rows
    const int w  = t >> 6;
    const int l  = t & 63;
    const int lr = l & 15;
    const int lg = l >> 4;
    const int lx = lr & 7;

    const int  Mraw    = Mg[b];
    const bool uniform = (Mraw < 0);
    const int  M       = uniform ? S : Mraw;
    const int  ntiles  = (M + 63) >> 6;

    // staging geometry: single pass, 512 threads x 16B = one 8KB tile per tensor
    const int r  = t >> 3;                               // linear row 0..63
    const int so = r * 64 + (((t & 7) ^ (r & 7)) << 3);  // pre-swizzled src (shorts)
    const int ld = w * 512;                              // wave-uniform LDS chunk (shorts)

    // ---- stage tile 0 (async) + idxs ----
    gload16(Ksrc + so, &Kt[0][0][0] + ld);
    gload16(Vsrc + so, &Vt[0][0][0] + ld);
    if (t < 64) idxs[0][t] = idxb[t];

    // ---- decay table (fp16): dtab[i] = 2^(-CD2*(q0+i-2047)^2), i in [0,2304) ----
    for (int i = t; i < 2304; i += 512) {
        const float rr = (float)(q0 + i - 2047);
        dtab[i] = (unsigned short)pkrtz(__builtin_exp2f(-CD2f * rr * rr), 0.f);
    }

    // ---- Q fragments (B-operand), scaled; zeroed in uniform mode ----
    const float qscale = uniform ? 0.0f : 0.125f * LOG2E;
    bf16x8 qf[2][2];
    #pragma unroll
    for (int rt = 0; rt < 2; ++rt) {
        const int row = w * 32 + rt * 16 + lr;
        #pragma unroll
        for (int g = 0; g < 2; ++g) {
            const float* src = Qp + row * D + g * 32 + lg * 8;
            union { unsigned u[4]; bf16x8 v; } cv;
            #pragma unroll
            for (int jj = 0; jj < 4; ++jj)
                cv.u[jj] = cvtpk(src[2 * jj] * qscale, src[2 * jj + 1] * qscale);
            qf[rt][g] = cv.v;
        }
    }

    f32x4 Oacc[2][4];
    #pragma unroll
    for (int rt = 0; rt < 2; ++rt)
        #pragma unroll
        for (int dt = 0; dt < 4; ++dt) Oacc[rt][dt] = f32x4{0.f, 0.f, 0.f, 0.f};
    float lrun[2] = {0.f, 0.f};

    const int qiA = w * 32 + lr + 2047;   // rt0 table index base
    const int qiB = qiA + 16;             // rt1

    asm volatile("s_waitcnt vmcnt(0)" ::: "memory");
    __syncthreads();

    int c = 0;
    for (int tt = 0; tt < ntiles; ++tt) {
        const int  rem  = M - tt * 64;
        const bool last = (rem <= 64);

        // ---- stage next tile (async; lands during compute) + idxs ----
        if (tt + 1 < ntiles) {
            const short* kp = Ksrc + (size_t)(tt + 1) * 4096;
            const short* vp = Vsrc + (size_t)(tt + 1) * 4096;
            gload16(kp + so, &Kt[c ^ 1][0][0] + ld);
            gload16(vp + so, &Vt[c ^ 1][0][0] + ld);
            if (t < 64) idxs[c ^ 1][t] = idxb[(tt + 1) * 64 + t];
        }

        const char* kbase = (const char*)&Kt[c][0][0];
        const char* vbase = (const char*)&Vt[c][0][0];

        #pragma unroll
        for (int kt = 0; kt < 4; ++kt) {
            // K fragments (swizzled b128) -> QK^T for both rt; C-init = -2 (shift)
            const bf16x8 kf0 = *(const bf16x8*)(kbase + (kt * 16 + lr) * 128
                                                + ((lg ^ lx) << 4));
            const bf16x8 kf1 = *(const bf16x8*)(kbase + (kt * 16 + lr) * 128
                                                + (((4 + lg) ^ lx) << 4));
            f32x4 s0 = f32x4{-2.f, -2.f, -2.f, -2.f};
            f32x4 s1 = f32x4{-2.f, -2.f, -2.f, -2.f};
            __builtin_amdgcn_s_setprio(1);
            s0 = __builtin_amdgcn_mfma_f32_16x16x32_bf16(kf0, qf[0][0], s0, 0, 0, 0);
            s0 = __builtin_amdgcn_mfma_f32_16x16x32_bf16(kf1, qf[0][1], s0, 0, 0, 0);
            s1 = __builtin_amdgcn_mfma_f32_16x16x32_bf16(kf0, qf[1][0], s1, 0, 0, 0);
            s1 = __builtin_amdgcn_mfma_f32_16x16x32_bf16(kf1, qf[1][1], s1, 0, 0, 0);
            __builtin_amdgcn_s_setprio(0);

            // original key indices from LDS (broadcast b128, conflict-free)
            const i32x4 iv = *(const i32x4*)&idxs[c][kt * 16 + lg * 4];

            // decay pair words from single fp16 table: lo = rt0, hi = rt1
            const unsigned dq0 = (unsigned)dtab[qiA - iv[0]] | ((unsigned)dtab[qiB - iv[0]] << 16);
            const unsigned dq1 = (unsigned)dtab[qiA - iv[1]] | ((unsigned)dtab[qiB - iv[1]] << 16);
            const unsigned dq2 = (unsigned)dtab[qiA - iv[2]] | ((unsigned)dtab[qiB - iv[2]] << 16);
            const unsigned dq3 = (unsigned)dtab[qiA - iv[3]] | ((unsigned)dtab[qiB - iv[3]] << 16);

            // fixed-shift softmax: p = 2^(s-2); shift cancels in O/l
            float pa0 = __builtin_exp2f(s0[0]), pb0 = __builtin_exp2f(s1[0]);
            float pa1 = __builtin_exp2f(s0[1]), pb1 = __builtin_exp2f(s1[1]);
            float pa2 = __builtin_exp2f(s0[2]), pb2 = __builtin_exp2f(s1[2]);
            float pa3 = __builtin_exp2f(s0[3]), pb3 = __builtin_exp2f(s1[3]);
            if (last) {   // zero padded keys (wave-uniform branch)
                const int ck = kt * 16 + lg * 4;
                pa0 = (ck + 0 < rem) ? pa0 : 0.f;  pb0 = (ck + 0 < rem) ? pb0 : 0.f;
                pa1 = (ck + 1 < rem) ? pa1 : 0.f;  pb1 = (ck + 1 < rem) ? pb1 : 0.f;
                pa2 = (ck + 2 < rem) ? pa2 : 0.f;  pb2 = (ck + 2 < rem) ? pb2 : 0.f;
                pa3 = (ck + 3 < rem) ? pa3 : 0.f;  pb3 = (ck + 3 < rem) ? pb3 : 0.f;
            }
            lrun[0] += (pa0 + pa1) + (pa2 + pa3);
            lrun[1] += (pb0 + pb1) + (pb2 + pb3);

            // pack p across rt, apply both decays with one pk_mul per element
            const unsigned pd0 = pkmul(pkrtz(pa0, pb0), dq0);
            const unsigned pd1 = pkmul(pkrtz(pa1, pb1), dq1);
            const unsigned pd2 = pkmul(pkrtz(pa2, pb2), dq2);
            const unsigned pd3 = pkmul(pkrtz(pa3, pb3), dq3);

            // reassemble per-rt B-fragments (f16): lo halves -> rt0, hi -> rt1
            union { unsigned u[2]; f16x4 v; } xb0, xb1;
            xb0.u[0] = __builtin_amdgcn_perm(pd1, pd0, 0x05040100u);
            xb0.u[1] = __builtin_amdgcn_perm(pd3, pd2, 0x05040100u);
            xb1.u[0] = __builtin_amdgcn_perm(pd1, pd0, 0x07060302u);
            xb1.u[1] = __builtin_amdgcn_perm(pd3, pd2, 0x07060302u);

            // PV for this 16-key slab (fp16 MFMA); vA shared across rt
            __builtin_amdgcn_s_setprio(1);
            #pragma unroll
            for (int dt = 0; dt < 4; ++dt) {
                const f16x4 vA = *(const f16x4*)(vbase + (dt * 16 + lr) * 128
                          + ((((2 * kt + (lg >> 1)) ^ lx) << 4) | ((lg & 1) << 3)));
                Oacc[0][dt] = mfma16h(vA, xb0.v, Oacc[0][dt]);
                Oacc[1][dt] = mfma16h(vA, xb1.v, Oacc[1][dt]);
            }
            __builtin_amdgcn_s_setprio(0);
        }

        asm volatile("s_waitcnt vmcnt(0)" ::: "memory");
        __syncthreads();
        c ^= 1;
    }

    // ---- epilogue ----
    #pragma unroll
    for (int rt = 0; rt < 2; ++rt) {
        float ls = lrun[rt];
        ls += __shfl_xor(ls, 16, 64);
        ls += __shfl_xor(ls, 32, 64);
        const float inv = 1.0f / ls;
        const int row = w * 32 + rt * 16 + lr;
        #pragma unroll
        for (int dt = 0; dt < 4; ++dt) {
            f32x4 o = Oacc[rt][dt];
            o[0] *= inv; o[1] *= inv; o[2] *= inv; o[3] *= inv;
            *(f32x4*)&Op[(size_t)row * D + dt * 16 + lg * 4] = o;
        }
    }
}

// ------- kernel 4: gather fallback (used if ws too small) -------
__global__ __launch_bounds__(256, 3) void attn_gather(
    const float* __restrict__ Qg, const float* __restrict__ Kg,
    const float* __restrict__ Vg, const int* __restrict__ idxp,
    const int* __restrict__ Mg, float* __restrict__ outg)
{
    __shared__ alignas(16) short Kt[64][72];
    __shared__ alignas(16) short Vt[64][72];
    __shared__ alignas(16) float dtab[2176];
    __shared__ alignas(16) int   idxs[64];

    const int blk = blockIdx.x;
    const int qt  = blk & 15;
    const int bh  = blk >> 4;
    const int b   = bh >> 4;
    const int q0  = qt * 128;

    const float* Qp = Qg + ((size_t)bh * S + q0) * D;
    const float* Kp = Kg + (size_t)bh * S * D;
    const float* Vp = Vg + (size_t)bh * S * D;
    float*       Op = outg + ((size_t)bh * S + q0) * D;
    const int*   idxb = idxp + b * S;

    const int t  = threadIdx.x;
    const int w  = t >> 6;
    const int l  = t & 63;
    const int lr = l & 15;
    const int lg = l >> 4;

    const int  Mraw    = Mg[b];
    const bool uniform = (Mraw < 0);
    const int  M       = uniform ? S : Mraw;

    for (int i = t; i < 2176; i += 256) {
        const float r = (float)(q0 + i - 2047);
        dtab[i] = __builtin_exp2f(-CD2f * r * r);
    }

    const float qscale = uniform ? 0.0f : 0.125f * LOG2E;
    bf16x8 qf[2][2];
    #pragma unroll
    for (int rt = 0; rt < 2; ++rt) {
        const int row = w * 32 + rt * 16 + lr;
        #pragma unroll
        for (int g = 0; g < 2; ++g) {
            const float* src = Qp + row * D + g * 32 + lg * 8;
            union { unsigned u[4]; bf16x8 v; } cv;
            #pragma unroll
            for (int jj = 0; jj < 4; ++jj)
                cv.u[jj] = cvtpk(src[2 * jj] * qscale, src[2 * jj + 1] * qscale);
            qf[rt][g] = cv.v;
        }
    }

    f32x4 Oacc[2][4];
    #pragma unroll
    for (int rt = 0; rt < 2; ++rt)
        #pragma unroll
        for (int dt = 0; dt < 4; ++dt) Oacc[rt][dt] = f32x4{0.f, 0.f, 0.f, 0.f};
    float lrun[2] = {0.f, 0.f};

    const int qrl2047 = w * 32 + lr + 2047;

    for (int kv = 0; kv < M; kv += 64) {
        const int  rem  = M - kv;
        const bool last = (rem <= 64);
        __syncthreads();
        {
            const int key = t >> 3;
            const int dc  = (t & 7) * 8;
            #pragma unroll
            for (int it = 0; it < 2; ++it) {
                const int row = idxb[kv + key + it * 32];
                const float* src = Kp + (size_t)row * D + dc;
                u32x4 pk;
                #pragma unroll
                for (int jj = 0; jj < 4; ++jj)
                    pk[jj] = cvtpk(src[2 * jj], src[2 * jj + 1]);
                *(u32x4*)&Kt[key + it * 32][dc] = pk;
            }
        }
        if (t < 64) idxs[t] = idxb[kv + t];
        {
            const int dv = t & 63;
            const int kb = (t >> 6) * 16;
            float f[16];
            #pragma unroll
            for (int i = 0; i < 16; ++i) {
                int row = idxb[kv + kb + i];
                row = __builtin_amdgcn_readfirstlane(row);
                f[i] = Vp[(size_t)row * D + dv];
            }
            u32x4 p0, p1;
            #pragma unroll
            for (int jj = 0; jj < 4; ++jj) {
                p0[jj] = cvtpk(f[2 * jj], f[2 * jj + 1]);
                p1[jj] = cvtpk(f[8 + 2 * jj], f[9 + 2 * jj]);
            }
            *(u32x4*)&Vt[dv][kb]     = p0;
            *(u32x4*)&Vt[dv][kb + 8] = p1;
        }
        __syncthreads();

        bf16x8 kf[4][2];
        #pragma unroll
        for (int kt = 0; kt < 4; ++kt)
            #pragma unroll
            for (int g = 0; g < 2; ++g)
                kf[kt][g] = *(const bf16x8*)&Kt[kt * 16 + lr][g * 32 + lg * 8];

        bf16x4 Xb[2][4];
        #pragma unroll
        for (int rt = 0; rt < 2; ++rt) {
            f32x4 sc[4];
            #pragma unroll
            for (int kt = 0; kt < 4; ++kt) {
                f32x4 acc = f32x4{-16.f, -16.f, -16.f, -16.f};
                acc = __builtin_amdgcn_mfma_f32_16x16x32_bf16(kf[kt][0], qf[rt][0], acc, 0, 0, 0);
                acc = __builtin_amdgcn_mfma_f32_16x16x32_bf16(kf[kt][1], qf[rt][1], acc, 0, 0, 0);
                sc[kt] = acc;
            }
            const int qi = qrl2047 + rt * 16;
            float lp = 0.f;
            #pragma unroll
            for (int kt = 0; kt < 4; ++kt) {
                const i32x4 iv = *(const i32x4*)&idxs[kt * 16 + lg * 4];
                float p0 = __builtin_exp2f(sc[kt][0]);
                float p1 = __builtin_exp2f(sc[kt][1]);
                float p2 = __builtin_exp2f(sc[kt][2]);
                float p3 = __builtin_exp2f(sc[kt][3]);
                if (last) {
                    const int ck = kt * 16 + lg * 4;
                    p0 = (ck + 0 < rem) ? p0 : 0.f;
                    p1 = (ck + 1 < rem) ? p1 : 0.f;
                    p2 = (ck + 2 < rem) ? p2 : 0.f;
                    p3 = (ck + 3 < rem) ? p3 : 0.f;
                }
                lp += (p0 + p1) + (p2 + p3);
                const float d0 = dtab[qi - iv[0]];
                const float d1 = dtab[qi - iv[1]];
                const float d2 = dtab[qi - iv[2]];
                const float d3 = dtab[qi - iv[3]];
                union { unsigned u[2]; bf16x4 v; } cx;
                cx.u[0] = cvtpk(p0 * d0, p1 * d1);
                cx.u[1] = cvtpk(p2 * d2, p3 * d3);
                Xb[rt][kt] = cx.v;
            }
            lrun[rt] += lp;
        }

        #pragma unroll
        for (int kt = 0; kt < 4; ++kt) {
            bf16x4 vA[4];
            #pragma unroll
            for (int dt = 0; dt < 4; ++dt)
                vA[dt] = *(const bf16x4*)&Vt[dt * 16 + lr][kt * 16 + lg * 4];
            #pragma unroll
            for (int dt = 0; dt < 4; ++dt) {
                Oacc[0][dt] = mfma16(vA[dt], Xb[0][kt], Oacc[0][dt]);
                Oacc[1][dt] = mfma16(vA[dt], Xb[1][kt], Oacc[1][dt]);
            }
        }
    }

    #pragma unroll
    for (int rt = 0; rt < 2; ++rt) {
        float ls = lrun[rt];
        ls += __shfl_xor(ls, 16, 64);
        ls += __shfl_xor(ls, 32, 64);
        const float inv = 1.0f / ls;
        const int row = w * 32 + rt * 16 + lr;
        #pragma unroll
        for (int dt = 0; dt < 4; ++dt) {
            f32x4 o = Oacc[rt][dt];
            o[0] *= inv; o[1] *= inv; o[2] *= inv; o[3] *= inv;
            *(f32x4*)&Op[(size_t)row * D + dt * 16 + lg * 4] = o;
        }
    }
}

extern "C" void kernel_launch(void* const* d_in, const int* in_sizes, int n_in,
                              void* d_out, int out_size, void* d_ws, size_t ws_size,
                              hipStream_t stream) {
    const float* Q = (const float*)d_in[0];
    const float* K = (const float*)d_in[1];
    const float* V = (const float*)d_in[2];
    const void*  M = d_in[3];
    float* out = (float*)d_out;

    int* idxp = (int*)d_ws;                       // Bn*S ints
    int* Mg   = idxp + Bn * S;                    // Bn ints
    size_t base = (((size_t)(Bn * S + Bn) * 4) + 255) & ~(size_t)255;
    short* Kw = (short*)((char*)d_ws + base);     // Bn*Hn*S*D bf16
    short* Vw = Kw + (size_t)Bn * Hn * S * D;     // Bn*Hn*S*D fp16
    const size_t need = base + 2 * (size_t)Bn * Hn * S * D * sizeof(short);

    compact_mask<<<dim3(Bn), dim3(256), 0, stream>>>(M, idxp, Mg);
    if (ws_size >= need) {
        pack_kv<<<dim3(Bn * Hn, S / 256), dim3(256), 0, stream>>>(K, V, idxp, Mg, Kw, Vw);
        attn_packed<<<dim3(Bn * Hn * (S / 256)), dim3(512), 0, stream>>>(Q, Kw, Vw, idxp, Mg, out);
    } else {
        attn_gather<<<dim3(Bn * Hn * (S / 128)), dim3(256), 0, stream>>>(Q, K, V, idxp, Mg, out);
    }
}